// Round 9
// baseline (39.928 us; speedup 1.0000x reference)
//
#include <hip/hip_runtime.h>

#define WSZ    64
#define BLOCK  256
#define INV2PI 0.15915494309189535f   // v_sin/v_cos take revolutions

// Constant-address-space view of the coef table: uniform compile-time indices
// off an AS(4) pointer lower to s_load (scalar cache), not per-lane VMEM.
typedef const __attribute__((address_space(4))) float cfloat;

// ---------------------------------------------------------------------------
// Writer: fold Rz(th1)*Ry(th0) into the 8-NZ Bloch 3x3 per step, to d_ws.
// Layout per step t: [m00 m01 m02 m10 m11 m12 m20 m22] (32 B, s_load_dwordx8).
// ---------------------------------------------------------------------------
__global__ void coef_kernel(const float* __restrict__ theta, float* __restrict__ coef) {
    int t = threadIdx.x;               // launched with exactly 64 threads
    float2 th = reinterpret_cast<const float2*>(theta)[t];
    float sa = __builtin_amdgcn_sinf(th.x * INV2PI);
    float ca = __builtin_amdgcn_cosf(th.x * INV2PI);
    float sb = __builtin_amdgcn_sinf(th.y * INV2PI);
    float cb = __builtin_amdgcn_cosf(th.y * INV2PI);
    float4* c4 = reinterpret_cast<float4*>(coef);
    c4[2 * t + 0] = make_float4(cb * ca, -sb, cb * sa, sb * ca);
    c4[2 * t + 1] = make_float4(cb, sb * sa, -sa, ca);
}

__global__ __launch_bounds__(BLOCK) void sq_main(
    const float* __restrict__ x,
    const float* __restrict__ coef,
    const float* __restrict__ w,
    const float* __restrict__ bias,
    float* __restrict__ out)
{
    // No LDS at all. Each thread streams its own 256B row (16 x float4, two
    // cache lines, fully consumed by this lane). Coefs arrive on the scalar
    // pipe; hot loop uses only VALU + trans + the streaming VMEM.
    const int tid = threadIdx.x;
    const size_t row = (size_t)blockIdx.x * BLOCK + tid;
    const float4* xr4 = reinterpret_cast<const float4*>(x + row * WSZ);
    cfloat* cf = (cfloat*)coef;

    const float wv = w[0];
    const float bv = bias[0];

    // ping-pong row buffers: <=32 data dwords live, all compile-time indexed
    float4 bufA[4], bufB[4];

    auto issue = [&](float4 (&b)[4], int g) {
        #pragma unroll
        for (int k = 0; k < 4; ++k) b[k] = xr4[g * 4 + k];
    };

    issue(bufA, 0);
    issue(bufB, 1);

    float vx = 0.0f, vy = 0.0f, vz = 1.0f;

    auto quarter = [&](float4 (&b)[4], int g) {
        __builtin_amdgcn_sched_barrier(0);   // cap hoisting window (R7 spill lesson)
        #pragma unroll
        for (int c = 0; c < 4; ++c) {
            float q[4] = {b[c].x, b[c].y, b[c].z, b[c].w};
            #pragma unroll
            for (int j = 0; j < 4; ++j) {
                const int t = g * 16 + c * 4 + j;      // compile-time step index
                cfloat* m = cf + t * 8;                // uniform -> s_load_dwordx8
                float r  = q[j] * INV2PI;
                float s  = __builtin_amdgcn_sinf(r);
                float co = __builtin_amdgcn_cosf(r);
                float y1 = co * vy - s  * vz;          // Rx(x_t)
                float z1 = s  * vy + co * vz;
                float nx = m[0] * vx + m[1] * y1 + m[2] * z1;
                float ny = m[3] * vx + m[4] * y1 + m[5] * z1;
                float nz = m[6] * vx + m[7] * z1;      // m21 == 0
                vx = nx; vy = ny; vz = nz;
            }
        }
    };

    quarter(bufA, 0);
    issue(bufA, 2);              // refill flies under quarter 1's compute
    quarter(bufB, 1);
    issue(bufB, 3);              // refill flies under quarter 2's compute
    quarter(bufA, 2);
    quarter(bufB, 3);

    out[row] = vz * wv + bv;
}

extern "C" void kernel_launch(void* const* d_in, const int* in_sizes, int n_in,
                              void* d_out, int out_size, void* d_ws, size_t ws_size,
                              hipStream_t stream) {
    const float* x     = (const float*)d_in[0];
    const float* theta = (const float*)d_in[1];
    const float* w     = (const float*)d_in[2];
    const float* b     = (const float*)d_in[3];
    float* out  = (float*)d_out;
    float* coef = (float*)d_ws;           // 64*8*4 = 2048 B scratch

    coef_kernel<<<1, WSZ, 0, stream>>>(theta, coef);

    int nrows = out_size;                 // B = 524288 (divisible by 256)
    int grid  = nrows / BLOCK;            // 2048 blocks
    sq_main<<<grid, BLOCK, 0, stream>>>(x, coef, w, b, out);
}